// Round 4
// baseline (269.519 us; speedup 1.0000x reference)
//
#include <hip/hip_runtime.h>

#define CH 256
#define HH 128
#define WW 128
#define HW (HH * WW)
#define SEGH 16   // rows per vertical segment
#define NSEG 8    // 128 / SEGH

__device__ __forceinline__ float rdlane(float v, int l) {
    return __int_as_float(__builtin_amdgcn_readlane(__float_as_int(v), l));
}
__device__ __forceinline__ float uni(float v) {
    return __int_as_float(__builtin_amdgcn_readfirstlane(__float_as_int(v)));
}

// One block per (b,c) image. 1024 threads (16 waves). LDS 72 KiB, 2 blocks/CU.
//
// x is read from GLOBAL exactly once (stage burst); the row->column transpose
// happens in LDS. Swizzled float4 slot within each row: P(hk,j) = (hk^2j)+8j
// (bijective; write/read/column patterns all measured conflict-free in r3).
//
//   Stage:   thread (hr,hk): 4 float4 global loads -> 4 b128 LDS writes.
//            Pure memory burst from all waves = max MLP on the only HBM read.
//   barrier #1
//   V1:      thread (col,seg): 16 b32 LDS column reads -> xv[16] regs
//            (live to the end), segment exit states b2/b3 -> scratch.
//   barrier #2  (all V1 reads done -> H may overwrite; scratch ready)
//   Fixup:   Sin/Tin from <=7 scratch summaries (wave-uniform trips).
//   H:       reload own row chunk xr[16] from LDS (4 b128), two-half Horner
//            compose, 3-step KS over 8 lanes, then in-place plane overwrite:
//            backward pass writes m1*rr, forward pass RMWs += m0*l.
//            Same-thread slots only -> no cross-thread hazard.
//   barrier #3
//   V2:      forward tb chain (x from regs) + swizzled plane read -> o[16];
//            backward bt chain + coalesced b32 stores.
__global__ __launch_bounds__(1024, 8) void dscan_kernel(
    const float* __restrict__ x,
    const float* __restrict__ decay_logits,
    const float* __restrict__ mix_logits,
    const float* __restrict__ input_scale,
    float* __restrict__ out)
{
    extern __shared__ float smem[];
    float* __restrict__ xs  = smem;           // 16384 floats: x-plane, then result plane
    float* __restrict__ scr = smem + HW;      // 2048 floats: b2 (1024) + b3 (1024)

    const int img  = blockIdx.x;              // b*256 + c
    const int c    = img & (CH - 1);
    const int tid  = threadIdx.x;
    const int lane = tid & 63;

    // ---- lane-split per-channel params ----
    float pv = 0.0f;
    {
        const int j = lane & 3;
        const int g = lane >> 2;
        if (g == 0) {
            const float v = decay_logits[j * CH + c];
            pv = fminf(fmaxf(1.0f / (1.0f + expf(-v)), 0.05f), 0.995f);
        } else if (g == 1) {
            const float a0 = mix_logits[0 * CH + c];
            const float a1 = mix_logits[1 * CH + c];
            const float a2 = mix_logits[2 * CH + c];
            const float a3 = mix_logits[3 * CH + c];
            const float mm = fmaxf(fmaxf(a0, a1), fmaxf(a2, a3));
            const float aj = (j == 0) ? a0 : (j == 1) ? a1 : (j == 2) ? a2 : a3;
            pv = expf(aj - mm);
        } else if (g == 2) {
            pv = 1.0f + tanhf(input_scale[j * CH + c]);
        }
    }
    const float d0 = rdlane(pv, 0), d1 = rdlane(pv, 1);
    const float d2 = rdlane(pv, 2), d3 = rdlane(pv, 3);
    const float e0 = rdlane(pv, 4), e1 = rdlane(pv, 5);
    const float e2 = rdlane(pv, 6), e3 = rdlane(pv, 7);
    const float s0 = rdlane(pv, 8), s1 = rdlane(pv, 9);
    const float s2 = rdlane(pv, 10), s3 = rdlane(pv, 11);

    const float einv = uni(1.0f / (e0 + e1 + e2 + e3));
    const float m0 = uni(e0 * einv), m1 = uni(e1 * einv);
    const float m2 = uni(e2 * einv), m3 = uni(e3 * einv);
    const float c0 = uni((1.0f - d0) * s0);   // s = d*s + c*x
    const float c1 = uni((1.0f - d1) * s1);
    const float c2 = uni((1.0f - d2) * s2);
    const float c3 = uni((1.0f - d3) * s3);

    // powers: p8 = d^8 (compose join), q[k] = d^(16*2^k) (KS steps)
    float p8_0, p8_1, q0[3], q1[3];
    {
        float a = d0 * d0; a = a * a;             // d0^4
        p8_0 = uni(a * a);                        // d0^8
        q0[0] = uni(p8_0 * p8_0); q0[1] = uni(q0[0] * q0[0]); q0[2] = uni(q0[1] * q0[1]);
        float b = d1 * d1; b = b * b;
        p8_1 = uni(b * b);
        q1[0] = uni(p8_1 * p8_1); q1[1] = uni(q1[0] * q1[0]); q1[2] = uni(q1[1] * q1[1]);
    }
    float t2v = d2 * d2; t2v = t2v * t2v; t2v = t2v * t2v; const float d2p16 = uni(t2v * t2v);
    float t3v = d3 * d3; t3v = t3v * t3v; t3v = t3v * t3v; const float d3p16 = uni(t3v * t3v);

    const float* __restrict__ xg = x + (size_t)img * HW;
    float* __restrict__ og = out + (size_t)img * HW;

    const int hr = tid >> 3;              // H row 0..127
    const int hk = tid & 7;               // H chunk 0..7
    float* __restrict__ prow = xs + hr * WW;

    // ---- Stage: the ONLY global read of x; pure burst ----
    {
        const float* __restrict__ xrow = xg + hr * WW + hk * 16;
        const float4 a0 = *(const float4*)(xrow + 0);
        const float4 a1 = *(const float4*)(xrow + 4);
        const float4 a2 = *(const float4*)(xrow + 8);
        const float4 a3 = *(const float4*)(xrow + 12);
        *(float4*)(prow + 4 * ((hk ^ 0) +  0)) = a0;   // slot P(hk,0)
        *(float4*)(prow + 4 * ((hk ^ 2) +  8)) = a1;   // slot P(hk,1)
        *(float4*)(prow + 4 * ((hk ^ 4) + 16)) = a2;   // slot P(hk,2)
        *(float4*)(prow + 4 * ((hk ^ 6) + 24)) = a3;   // slot P(hk,3)
    }

    __syncthreads();   // #1: x-plane complete

    // ---- V1: column reads from LDS, segment summaries ----
    const int col = tid & (WW - 1);       // 0..127
    const int seg = tid >> 7;             // 0..7
    // row-independent swizzled float offset for this column
    const int coff = 4 * (((col >> 4) ^ (2 * ((col >> 2) & 3))) + 8 * ((col >> 2) & 3))
                   + (col & 3);
    float xv[SEGH];                       // x column chunk, lives to the end
    {
        const float* __restrict__ pcol = xs + seg * SEGH * WW + coff;
#pragma unroll
        for (int i = 0; i < SEGH; ++i) xv[i] = pcol[i * WW];

        float b2 = 0.0f;
#pragma unroll
        for (int i = 0; i < SEGH; ++i) b2 = fmaf(d2, b2, c2 * xv[i]);

        float b3 = 0.0f;                  // backward Horner: sum d3^i * xv[i]
#pragma unroll
        for (int i = SEGH - 1; i >= 0; --i) b3 = fmaf(d3, b3, xv[i]);
        b3 *= c3;

        scr[tid]        = b2;
        scr[1024 + tid] = b3;
    }

    __syncthreads();   // #2: V1 reads done (H may overwrite), scratch ready

    // ---- Fixup: incoming vertical states; wave-uniform trip counts ----
    float Sin = 0.0f;
    for (int j = 0; j < seg; ++j)
        Sin = fmaf(d2p16, Sin, scr[j * WW + col]);
    float Tin = 0.0f;
    for (int j = NSEG - 1; j > seg; --j)
        Tin = fmaf(d3p16, Tin, scr[1024 + j * WW + col]);

    // ---- H: row scans, in-place plane overwrite ----
    {
        float xr[16];
        {
            const float4 r0 = *(const float4*)(prow + 4 * ((hk ^ 0) +  0));
            const float4 r1 = *(const float4*)(prow + 4 * ((hk ^ 2) +  8));
            const float4 r2 = *(const float4*)(prow + 4 * ((hk ^ 4) + 16));
            const float4 r3 = *(const float4*)(prow + 4 * ((hk ^ 6) + 24));
            xr[0]=r0.x;  xr[1]=r0.y;  xr[2]=r0.z;  xr[3]=r0.w;
            xr[4]=r1.x;  xr[5]=r1.y;  xr[6]=r1.z;  xr[7]=r1.w;
            xr[8]=r2.x;  xr[9]=r2.y;  xr[10]=r2.z; xr[11]=r2.w;
            xr[12]=r3.x; xr[13]=r3.y; xr[14]=r3.z; xr[15]=r3.w;
        }

        // local compose, two independent 8-deep halves per direction
        float blo = c0 * xr[0];
#pragma unroll
        for (int i = 1; i < 8; ++i)  blo = fmaf(d0, blo, c0 * xr[i]);
        float bhi = c0 * xr[8];
#pragma unroll
        for (int i = 9; i < 16; ++i) bhi = fmaf(d0, bhi, c0 * xr[i]);
        float bL = fmaf(p8_0, blo, bhi);

        float rA = c1 * xr[15];
#pragma unroll
        for (int i = 14; i >= 8; --i) rA = fmaf(d1, rA, c1 * xr[i]);
        float rB = c1 * xr[7];
#pragma unroll
        for (int i = 6; i >= 0; --i)  rB = fmaf(d1, rB, c1 * xr[i]);
        float bR = fmaf(p8_1, rA, rB);

        // constant-decay Kogge-Stone over the 8 chunks of this row
#pragma unroll
        for (int kk = 0; kk < 3; ++kk) {
            const int off = 1 << kk;
            const float bU = __shfl_up(bL, (unsigned)off, 8);
            bL = fmaf(q0[kk], (hk >= off) ? bU : 0.0f, bL);
            const float bD = __shfl_down(bR, (unsigned)off, 8);
            bR = fmaf(q1[kk], (hk < 8 - off) ? bD : 0.0f, bR);
        }
        // exclusive incoming states
        float EL = __shfl_up(bL, 1u, 8);
        if (hk == 0) EL = 0.0f;
        float ER = __shfl_down(bR, 1u, 8);
        if (hk == 7) ER = 0.0f;

        // backward pass: write m1*rr into own slots (same t-chain order as r3)
        float t = ER;
#pragma unroll
        for (int j = 3; j >= 0; --j) {
            float4 o4;
            t = fmaf(d1, t, c1 * xr[4*j + 3]); o4.w = m1 * t;
            t = fmaf(d1, t, c1 * xr[4*j + 2]); o4.z = m1 * t;
            t = fmaf(d1, t, c1 * xr[4*j + 1]); o4.y = m1 * t;
            t = fmaf(d1, t, c1 * xr[4*j + 0]); o4.x = m1 * t;
            *(float4*)(prow + 4 * ((hk ^ (2*j)) + 8*j)) = o4;
        }
        // forward pass: RMW += m0*l (same-thread slots; program order safe)
        float l = EL;
#pragma unroll
        for (int j = 0; j < 4; ++j) {
            float* __restrict__ sp = prow + 4 * ((hk ^ (2*j)) + 8*j);
            float4 h4 = *(float4*)sp;
            l = fmaf(d0, l, c0 * xr[4*j + 0]); h4.x = fmaf(m0, l, h4.x);
            l = fmaf(d0, l, c0 * xr[4*j + 1]); h4.y = fmaf(m0, l, h4.y);
            l = fmaf(d0, l, c0 * xr[4*j + 2]); h4.z = fmaf(m0, l, h4.z);
            l = fmaf(d0, l, c0 * xr[4*j + 3]); h4.w = fmaf(m0, l, h4.w);
            *(float4*)sp = h4;
        }
    }

    __syncthreads();   // #3: result plane complete

    // ---- V2: forward tb + swizzled plane read; backward bt + store ----
    {
        const int rbase = seg * SEGH;
        const float* __restrict__ pcol = xs + rbase * WW + coff;

        float o[SEGH];
        float s = Sin;
#pragma unroll
        for (int i = 0; i < SEGH; ++i) {
            s = fmaf(d2, s, c2 * xv[i]);
            o[i] = fmaf(m2, s, pcol[i * WW]);
        }
        float t = Tin;
        float* __restrict__ ocol = og + rbase * WW + col;
#pragma unroll
        for (int i = SEGH - 1; i >= 0; --i) {
            t = fmaf(d3, t, c3 * xv[i]);
            ocol[i * WW] = fmaf(m3, t, o[i]);
        }
    }
}

extern "C" void kernel_launch(void* const* d_in, const int* in_sizes, int n_in,
                              void* d_out, int out_size, void* d_ws, size_t ws_size,
                              hipStream_t stream) {
    const float* x  = (const float*)d_in[0];
    const float* dl = (const float*)d_in[1];
    const float* ml = (const float*)d_in[2];
    const float* is = (const float*)d_in[3];
    float* out = (float*)d_out;

    const size_t lds_bytes = (size_t)(HW + 2048) * sizeof(float);   // 73728

    static bool attr_set = false;   // idempotent host-side attribute; value never changes
    if (!attr_set) {
        (void)hipFuncSetAttribute((const void*)dscan_kernel,
                                  hipFuncAttributeMaxDynamicSharedMemorySize,
                                  (int)lds_bytes);
        attr_set = true;
    }

    dim3 grid(2048), block(1024);
    hipLaunchKernelGGL(dscan_kernel, grid, block, lds_bytes, stream, x, dl, ml, is, out);
}